// Round 9
// baseline (211.353 us; speedup 1.0000x reference)
//
#include <hip/hip_runtime.h>
#include <hip/hip_bf16.h>

// PhraseClassifier R9.
//   proj_gemm: A staged as FULL CONTIGUOUS 4KB rows (kills the 4KB-stride
//     L2/L3 channel aliasing that pinned R5-R8 at ~73us). Block = 32 M-rows,
//     both halves: stage 128KB linear -> LDS (AU|AV bf16) -> phase U (16
//     K-iters, A from LDS, B global->VGPR, NO barriers -> compiler pipelines)
//     -> epilogue U (Eb overlays AU) -> phase V -> epilogue V. 2 barriers.
//     fp8 output, pair layout Wq[r] = [U[r] | V[r+32]].
//   span_eval: unchanged (two contiguous 1KB rows/span, depth-3 pipeline,
//     block partials, no atomics).

typedef float f32x4 __attribute__((ext_vector_type(4)));
typedef float f32x2 __attribute__((ext_vector_type(2)));
typedef __bf16 bf16x8 __attribute__((ext_vector_type(8)));

__device__ __forceinline__ unsigned short f2bf(float f) {
  unsigned int u = __float_as_uint(f);
  u += 0x7fffu + ((u >> 16) & 1u);   // RNE
  return (unsigned short)(u >> 16);
}
__device__ __forceinline__ float bf2f(unsigned int lo16) {
  return __uint_as_float(lo16 << 16);
}

// ---------------- prep: W1 [1024][512] fp32 -> W1t [512][1024] bf16 ----------------
__global__ void w1_transpose(const float* __restrict__ W1, unsigned short* __restrict__ W1t) {
  __shared__ float tile[32][33];
  int k0 = blockIdx.x * 32, n0 = blockIdx.y * 32;
  int tx = threadIdx.x, ty = threadIdx.y;  // 32 x 8
#pragma unroll
  for (int r = 0; r < 4; ++r)
    tile[ty + r * 8][tx] = W1[(k0 + ty + r * 8) * 512 + n0 + tx];
  __syncthreads();
#pragma unroll
  for (int r = 0; r < 4; ++r)
    W1t[(n0 + ty + r * 8) * 1024 + k0 + tx] = f2bf(tile[tx][ty + r * 8]);
}

// ---------------- proj_gemm: 32 M-rows/block, full-row contiguous staging ----------
// Grid (512): block rows r0..r0+31. Wave w owns N cols [w*128, w*128+128).
// AU/AV row stride 520 shorts (1040B, 16B-aligned; word-stride 260 ≡ 4 mod 32
// -> b128 frag reads spread words evenly over banks).
#define APITCH 520
__global__ __launch_bounds__(256, 2) void proj_gemm(
    const float* __restrict__ hidden,        // [16384][1024]
    const unsigned short* __restrict__ w1t,  // [512][1024] bf16
    unsigned char* __restrict__ Wq) {        // [16384][1024] fp8: [U[r] | V[r+32]]
  __shared__ __align__(16) unsigned short smem[34048];  // 68096 B
  unsigned short* AU = smem;            // [32][520]  (16640 shorts)
  unsigned short* AV = smem + 17408;    // [32][520]
  unsigned short* Eb = smem;            // overlay [4][32][136] (17408 shorts)

  const int t = threadIdx.x;
  const int lane = t & 63;
  const int w = t >> 6;
  const int r0 = blockIdx.x << 5;
  const int kq = (lane >> 4) << 3;      // k subchunk within BK=32 (0/8/16/24)

  // ---- stage: 8 passes x 4 rows; thread covers 64B (16 fp32) contiguous.
  // Block sweep = 32 full 4KB rows = 128KB linear (channel-uniform).
  {
    const int c16 = t & 63;             // 16-col chunk 0..63 (cols c16*16)
    const int rsub = t >> 6;            // row within pass group
#pragma unroll 4
    for (int p = 0; p < 8; ++p) {
      int row = (p << 2) + rsub;        // 0..31
      const float4* gp = (const float4*)(hidden + ((r0 + row) << 10) + (c16 << 4));
      float4 f0 = gp[0], f1 = gp[1], f2 = gp[2], f3 = gp[3];
      uint4 a, b;
      a.x = (unsigned)f2bf(f0.x) | ((unsigned)f2bf(f0.y) << 16);
      a.y = (unsigned)f2bf(f0.z) | ((unsigned)f2bf(f0.w) << 16);
      a.z = (unsigned)f2bf(f1.x) | ((unsigned)f2bf(f1.y) << 16);
      a.w = (unsigned)f2bf(f1.z) | ((unsigned)f2bf(f1.w) << 16);
      b.x = (unsigned)f2bf(f2.x) | ((unsigned)f2bf(f2.y) << 16);
      b.y = (unsigned)f2bf(f2.z) | ((unsigned)f2bf(f2.w) << 16);
      b.z = (unsigned)f2bf(f3.x) | ((unsigned)f2bf(f3.y) << 16);
      b.w = (unsigned)f2bf(f3.z) | ((unsigned)f2bf(f3.w) << 16);
      unsigned short* dst = (c16 < 32) ? (AU + row * APITCH + (c16 << 4))
                                       : (AV + row * APITCH + ((c16 - 32) << 4));
      *(uint4*)dst = a;
      *(uint4*)(dst + 8) = b;
    }
  }
  __syncthreads();

  // B frag global offsets (shorts): row n = w*128 + nt*16 + (lane&15) of W1t
  int boffn[8];
#pragma unroll
  for (int nt = 0; nt < 8; ++nt)
    boffn[nt] = (((w << 7) + (nt << 4) + (lane & 15)) << 10) + kq;

  const int arow = lane & 15;

  // ================= phase U (k 0..511) =================
  f32x4 acc[2][8];
#pragma unroll
  for (int i = 0; i < 2; ++i)
#pragma unroll
    for (int j = 0; j < 8; ++j) acc[i][j] = (f32x4){0.f, 0.f, 0.f, 0.f};

#pragma unroll
  for (int it = 0; it < 16; ++it) {
    const int k0 = it << 5;
    bf16x8 af0 = *(const bf16x8*)(AU + arow * APITCH + k0 + kq);
    bf16x8 af1 = *(const bf16x8*)(AU + (16 + arow) * APITCH + k0 + kq);
    bf16x8 bfr[8];
#pragma unroll
    for (int nt = 0; nt < 8; ++nt)
      bfr[nt] = *(const bf16x8*)(w1t + boffn[nt] + k0);
#pragma unroll
    for (int nt = 0; nt < 8; ++nt) {
      acc[0][nt] = __builtin_amdgcn_mfma_f32_16x16x32_bf16(af0, bfr[nt], acc[0][nt], 0, 0, 0);
      acc[1][nt] = __builtin_amdgcn_mfma_f32_16x16x32_bf16(af1, bfr[nt], acc[1][nt], 0, 0, 0);
    }
  }
  __syncthreads();   // all waves done reading AU -> Eb may overlay it

  // ---- epilogue U: wave-local repack + coalesced fp8 stores
  // C/D layout: col = lane&15, row = (lane>>4)*4 + reg.
#pragma unroll
  for (int mt = 0; mt < 2; ++mt)
#pragma unroll
    for (int r = 0; r < 4; ++r) {
      int rr = (mt << 4) + ((lane >> 4) << 2) + r;   // 0..31
#pragma unroll
      for (int nt = 0; nt < 8; ++nt)
        Eb[((w << 5) + rr) * 136 + (nt << 4) + (lane & 15)] = f2bf(acc[mt][nt][r]);
    }
#pragma unroll
  for (int i = 0; i < 8; ++i) {
    int task = (i << 6) + lane;         // 512 tasks: 32 rows x 16 chunks
    int rr = task >> 4;
    int ck = task & 15;
    uint4 v = *(const uint4*)&Eb[((w << 5) + rr) * 136 + (ck << 3)];
    float f0 = bf2f(v.x & 0xffff), f1 = bf2f(v.x >> 16);
    float f2 = bf2f(v.y & 0xffff), f3 = bf2f(v.y >> 16);
    float f4 = bf2f(v.z & 0xffff), f5 = bf2f(v.z >> 16);
    float f6 = bf2f(v.w & 0xffff), f7 = bf2f(v.w >> 16);
    uint2 o;
    o.x = __builtin_amdgcn_cvt_pk_fp8_f32(f0, f1, 0, false);
    o.x = __builtin_amdgcn_cvt_pk_fp8_f32(f2, f3, o.x, true);
    o.y = __builtin_amdgcn_cvt_pk_fp8_f32(f4, f5, 0, false);
    o.y = __builtin_amdgcn_cvt_pk_fp8_f32(f6, f7, o.y, true);
    int grow = r0 + rr;
    *(uint2*)(Wq + (grow << 10) + (w << 7) + (ck << 3)) = o;   // U[r]
  }

  // ================= phase V (k 512..1023) =================
#pragma unroll
  for (int i = 0; i < 2; ++i)
#pragma unroll
    for (int j = 0; j < 8; ++j) acc[i][j] = (f32x4){0.f, 0.f, 0.f, 0.f};

#pragma unroll
  for (int it = 0; it < 16; ++it) {
    const int k0 = it << 5;
    bf16x8 af0 = *(const bf16x8*)(AV + arow * APITCH + k0 + kq);
    bf16x8 af1 = *(const bf16x8*)(AV + (16 + arow) * APITCH + k0 + kq);
    bf16x8 bfr[8];
#pragma unroll
    for (int nt = 0; nt < 8; ++nt)
      bfr[nt] = *(const bf16x8*)(w1t + boffn[nt] + 512 + k0);
#pragma unroll
    for (int nt = 0; nt < 8; ++nt) {
      acc[0][nt] = __builtin_amdgcn_mfma_f32_16x16x32_bf16(af0, bfr[nt], acc[0][nt], 0, 0, 0);
      acc[1][nt] = __builtin_amdgcn_mfma_f32_16x16x32_bf16(af1, bfr[nt], acc[1][nt], 0, 0, 0);
    }
  }
  // No barrier: Eb(=AU) is untouched since epilogue U; AV reads are mine.

  // ---- epilogue V: V[grow] stored at Wq row grow-32, cols 512..1023
#pragma unroll
  for (int mt = 0; mt < 2; ++mt)
#pragma unroll
    for (int r = 0; r < 4; ++r) {
      int rr = (mt << 4) + ((lane >> 4) << 2) + r;
#pragma unroll
      for (int nt = 0; nt < 8; ++nt)
        Eb[((w << 5) + rr) * 136 + (nt << 4) + (lane & 15)] = f2bf(acc[mt][nt][r]);
    }
#pragma unroll
  for (int i = 0; i < 8; ++i) {
    int task = (i << 6) + lane;
    int rr = task >> 4;
    int ck = task & 15;
    uint4 v = *(const uint4*)&Eb[((w << 5) + rr) * 136 + (ck << 3)];
    float f0 = bf2f(v.x & 0xffff), f1 = bf2f(v.x >> 16);
    float f2 = bf2f(v.y & 0xffff), f3 = bf2f(v.y >> 16);
    float f4 = bf2f(v.z & 0xffff), f5 = bf2f(v.z >> 16);
    float f6 = bf2f(v.w & 0xffff), f7 = bf2f(v.w >> 16);
    uint2 o;
    o.x = __builtin_amdgcn_cvt_pk_fp8_f32(f0, f1, 0, false);
    o.x = __builtin_amdgcn_cvt_pk_fp8_f32(f2, f3, o.x, true);
    o.y = __builtin_amdgcn_cvt_pk_fp8_f32(f4, f5, 0, false);
    o.y = __builtin_amdgcn_cvt_pk_fp8_f32(f6, f7, o.y, true);
    int grow = r0 + rr;
    if (grow >= 32)
      *(uint2*)(Wq + ((grow - 32) << 10) + 512 + (w << 7) + (ck << 3)) = o;
  }
}

// ---------------- span_eval: 1 span per half-wave, LDS meta, depth-3 pipeline ----
#define SPB 64
__global__ __launch_bounds__(256) void span_eval(
    const unsigned char* __restrict__ Wq,
    const int* __restrict__ bids, const int* __restrict__ begins,
    const int* __restrict__ ends, const int* __restrict__ flags,
    const float* __restrict__ weights,
    const float* __restrict__ b1, const float* __restrict__ w2,
    const float* __restrict__ b2, float* __restrict__ partials) {
  __shared__ int oB[SPB], oE[SPB], sfl[SPB];
  __shared__ float swt[SPB];
  __shared__ float red[4][3];
  const int t = threadIdx.x;
  const int lane = t & 63;
  const int w = t >> 6;
  const int h = lane >> 5;          // half-wave
  const int hl = lane & 31;
  const int sbase = blockIdx.x * SPB;

  if (t < SPB) {
    int s = sbase + t;
    int b = bids[s], bg = begins[s], en = ends[s];
    oB[t] = (((bg - 1) << 5) + b) << 10;   // row b-1: [U[b-1] | V[b]]
    oE[t] = (((en - 1) << 5) + b) << 10;   // row e-1: [U[e-1] | V[e]]
    sfl[t] = flags[s];
    swt[t] = weights[s];
  }
  __syncthreads();

  const int sp0 = ((w << 1) + h) << 3;   // my half-wave's first span (block-local)
  const int c0 = hl << 4;                // 16 u-cols per lane
  float b1v[16], w2v[16];
#pragma unroll
  for (int q = 0; q < 4; ++q) {
    float4 bv = *(const float4*)(b1 + c0 + (q << 2));
    float4 wv = *(const float4*)(w2 + c0 + (q << 2));
    b1v[(q << 2) + 0] = bv.x; b1v[(q << 2) + 1] = bv.y;
    b1v[(q << 2) + 2] = bv.z; b1v[(q << 2) + 3] = bv.w;
    w2v[(q << 2) + 0] = wv.x; w2v[(q << 2) + 1] = wv.y;
    w2v[(q << 2) + 2] = wv.z; w2v[(q << 2) + 3] = wv.w;
  }

  auto dec = [](unsigned int v, float* f) {
    f32x2 a = __builtin_amdgcn_cvt_pk_f32_fp8(v, false);
    f32x2 b = __builtin_amdgcn_cvt_pk_f32_fp8(v, true);
    f[0] = a[0]; f[1] = a[1]; f[2] = b[0]; f[3] = b[1];
  };

  uint4 BU[3], BV[3], EU[3], EV[3];
  auto ld = [&](int slot, int j) {
    int ob = oB[sp0 + j], oe = oE[sp0 + j];
    BU[slot] = *(const uint4*)(Wq + ob + c0);        // U[b-1] chunk
    BV[slot] = *(const uint4*)(Wq + ob + 512 + c0);  // V[b]   chunk
    EU[slot] = *(const uint4*)(Wq + oe + c0);        // U[e-1] chunk
    EV[slot] = *(const uint4*)(Wq + oe + 512 + c0);  // V[e]   chunk
  };
  ld(0, 0); ld(1, 1); ld(2, 2);

  float mylogit = 0.f;
#pragma unroll
  for (int j = 0; j < 8; ++j) {
    const int slot = j % 3;
    float buf[16], bvf[16], euf[16], evf[16];
    dec(BU[slot].x, buf); dec(BU[slot].y, buf + 4);
    dec(BU[slot].z, buf + 8); dec(BU[slot].w, buf + 12);
    dec(BV[slot].x, bvf); dec(BV[slot].y, bvf + 4);
    dec(BV[slot].z, bvf + 8); dec(BV[slot].w, bvf + 12);
    dec(EU[slot].x, euf); dec(EU[slot].y, euf + 4);
    dec(EU[slot].z, euf + 8); dec(EU[slot].w, euf + 12);
    dec(EV[slot].x, evf); dec(EV[slot].y, evf + 4);
    dec(EV[slot].z, evf + 8); dec(EV[slot].w, evf + 12);
    if (j + 3 < 8) ld(slot, j + 3);
    float sv = 0.f;
#pragma unroll
    for (int k = 0; k < 16; ++k) {
      float zp = euf[k] - buf[k] + bvf[k] - evf[k] + b1v[k];
      sv += fmaxf(zp, 0.f) * w2v[k];
    }
    sv += __shfl_xor(sv, 1);
    sv += __shfl_xor(sv, 2);
    sv += __shfl_xor(sv, 4);
    sv += __shfl_xor(sv, 8);
    sv += __shfl_xor(sv, 16);       // reduce within half-wave
    if (hl == j) mylogit = sv;      // lane h*32+j parks span sp0+j
  }

  // span w*16+l (l<16) parked at lane ((l&8)<<2)+(l&7)
  mylogit = __shfl(mylogit, ((lane & 8) << 2) + (lane & 7));

  float pos_t = 0.f, neg_t = 0.f, cnt_t = 0.f;
  if (lane < 16) {
    int sl = (w << 4) + lane;       // block-local span id
    float logit = mylogit + b2[0];
    float p = 1.f / (1.f + expf(-logit));
    p = fminf(fmaxf(p, 1e-7f), 1.f - 1e-7f);
    int fl = sfl[sl];
    float bce = (fl == 1) ? -logf(p) : -logf(1.f - p);
    float term = swt[sl] * bce;
    pos_t = (fl == 1) ? term : 0.f;
    neg_t = (fl == 1) ? 0.f : term;
    cnt_t = (fl == 1) ? 1.f : 0.f;
  }
#pragma unroll
  for (int off = 1; off < 64; off <<= 1) {
    pos_t += __shfl_xor(pos_t, off);
    neg_t += __shfl_xor(neg_t, off);
    cnt_t += __shfl_xor(cnt_t, off);
  }
  if (lane == 0) { red[w][0] = pos_t; red[w][1] = neg_t; red[w][2] = cnt_t; }
  __syncthreads();
  if (t == 0) {
    partials[(blockIdx.x << 2) + 0] = red[0][0] + red[1][0] + red[2][0] + red[3][0];
    partials[(blockIdx.x << 2) + 1] = red[0][1] + red[1][1] + red[2][1] + red[3][1];
    partials[(blockIdx.x << 2) + 2] = red[0][2] + red[1][2] + red[2][2] + red[3][2];
  }
}

// ---------------- finalize ----------------
__global__ void finalize(const float* __restrict__ parts, int nblk,
                         float* __restrict__ out, int nspans) {
  __shared__ float sp[4], sn[4], sc[4];
  float P = 0.f, Ng = 0.f, C = 0.f;
  for (int i = threadIdx.x; i < nblk; i += 256) {
    P += parts[(i << 2) + 0];
    Ng += parts[(i << 2) + 1];
    C += parts[(i << 2) + 2];
  }
#pragma unroll
  for (int off = 1; off < 64; off <<= 1) {
    P += __shfl_xor(P, off);
    Ng += __shfl_xor(Ng, off);
    C += __shfl_xor(C, off);
  }
  int w = threadIdx.x >> 6;
  if ((threadIdx.x & 63) == 0) { sp[w] = P; sn[w] = Ng; sc[w] = C; }
  __syncthreads();
  if (threadIdx.x == 0) {
    P = sp[0] + sp[1] + sp[2] + sp[3];
    Ng = sn[0] + sn[1] + sn[2] + sn[3];
    C = sc[0] + sc[1] + sc[2] + sc[3];
    float scale = 2.f * C / (float)nspans;
    out[0] = (P + scale * Ng) / (float)nspans;
  }
}

extern "C" void kernel_launch(void* const* d_in, const int* in_sizes, int n_in,
                              void* d_out, int out_size, void* d_ws, size_t ws_size,
                              hipStream_t stream) {
  const float* hidden = (const float*)d_in[0];
  const int* bids     = (const int*)d_in[1];
  const int* begins   = (const int*)d_in[2];
  const int* ends     = (const int*)d_in[3];
  const int* flags    = (const int*)d_in[4];
  const float* weights = (const float*)d_in[5];
  const float* W1 = (const float*)d_in[6];
  const float* b1 = (const float*)d_in[7];
  const float* W2 = (const float*)d_in[8];
  const float* b2 = (const float*)d_in[9];
  float* out = (float*)d_out;
  const int nspans = in_sizes[1];       // 131072
  const int nblk = nspans / SPB;        // 2048

  float* partials = (float*)d_ws;                                    // 32 KiB
  unsigned short* W1t = (unsigned short*)((char*)d_ws + (1 << 18));  // 1 MiB
  unsigned char* Wq = (unsigned char*)((char*)d_ws + (2 << 20));     // 16.8 MiB

  w1_transpose<<<dim3(32, 16), dim3(32, 8), 0, stream>>>(W1, W1t);
  proj_gemm<<<512, 256, 0, stream>>>(hidden, W1t, Wq);
  span_eval<<<nblk, 256, 0, stream>>>(Wq, bids, begins, ends, flags, weights,
                                      b1, W2, b2, partials);
  finalize<<<1, 256, 0, stream>>>(partials, nblk, out, nspans);
}

// Round 10
// 175.337 us; speedup vs baseline: 1.2054x; 1.2054x over previous
//
#include <hip/hip_runtime.h>
#include <hip/hip_bf16.h>

// PhraseClassifier R10.
//   Root cause of the 73-84us proj plateau (R5-R9): every B-fragment read was
//   16 x 64B segments at 2KB stride per wave instruction; the TCP processes
//   scattered segments ~5x slower than contiguous (measured 66us for 2MB/CU).
//   Fix: W1 is pre-converted to a K-CHUNK-BLOCKED layout W1b[c][n][kk]
//   (c = K/32 tile, 32KB contiguous per tile) so direct global->VGPR B-frag
//   loads cover a perfectly contiguous 1KB range. No LDS for B, no barriers
//   in the K-loop. A staged as contiguous full half-rows in LDS (R9 pattern).
//   M-tile 64 rows, halves split over blockIdx.y -> per-CU B traffic 1MB.
//   span_eval / finalize unchanged from R7-R9 (passed, 53us).

typedef float f32x4 __attribute__((ext_vector_type(4)));
typedef float f32x2 __attribute__((ext_vector_type(2)));
typedef __bf16 bf16x8 __attribute__((ext_vector_type(8)));

__device__ __forceinline__ unsigned short f2bf(float f) {
  unsigned int u = __float_as_uint(f);
  u += 0x7fffu + ((u >> 16) & 1u);   // RNE
  return (unsigned short)(u >> 16);
}
__device__ __forceinline__ float bf2f(unsigned int lo16) {
  return __uint_as_float(lo16 << 16);
}

// ---- prep: W1 [1024][512] fp32 -> W1b blocked [c=32][n=512][kk=32] bf16 ----
// Element (c, n, kk) = W1[c*32+kk][n]. 65536 threads; reads coalesced per
// (kc,j) (16 consecutive n x 4B = 64B segments), writes fully contiguous.
__global__ void w1_blocked(const float* __restrict__ W1,
                           unsigned short* __restrict__ W1b) {
  int idx = blockIdx.x * 256 + threadIdx.x;   // 0..65535
  int kc = idx & 3;                           // 8-k chunk within tile
  int n  = (idx >> 2) & 511;
  int c  = idx >> 11;                         // 0..31
  int k0 = c * 32 + kc * 8;
  unsigned short tmp[8];
#pragma unroll
  for (int j = 0; j < 8; ++j)
    tmp[j] = f2bf(W1[(k0 + j) * 512 + n]);
  *(uint4*)(W1b + c * 16384 + n * 32 + kc * 8) = *(uint4*)tmp;
}

// ---------------- proj_gemm: 64M x 512N per block, one K-half ----------------
// Grid (256, 2): x = M-group (64 rows), y = half (0: U, k/cols 0..511; 1: V).
// Wave w owns N cols [w*128, w*128+128): acc 4m x 8n. A from LDS (contiguous
// staged), B frags DIRECT global->VGPR from W1b (1KB contiguous per load).
#define APITCH 520
__global__ __launch_bounds__(256, 2) void proj_gemm(
    const float* __restrict__ hidden,        // [16384][1024]
    const unsigned short* __restrict__ w1b,  // blocked [32][512][32] bf16
    unsigned char* __restrict__ Wq) {        // [16384][1024] fp8: [U[r] | V[r+32]]
  __shared__ __align__(16) unsigned short AH[64 * APITCH];  // 66560 B
  unsigned short* Eb = AH;                   // overlay [4][32][136] = 17408 shorts

  const int t = threadIdx.x;
  const int lane = t & 63;
  const int w = t >> 6;
  const int r0 = blockIdx.x << 6;
  const int hk = blockIdx.y << 9;            // 0 (U) or 512 (V)
  const int q = lane >> 4;                   // k-sub 0..3
  const int m = lane & 15;

  // ---- stage A: 64 rows x 512 cols (one half) fp32 -> bf16 LDS.
  // Thread reads 64B contiguous; wave = 2 rows x 2KB contiguous sweeps.
  {
    const int col = (t & 31) << 4;           // 0,16,...,496
    const int rsub = t >> 5;                 // 0..7
#pragma unroll
    for (int p = 0; p < 8; ++p) {
      int row = (p << 3) + rsub;             // 0..63
      const float4* gp = (const float4*)(hidden + ((r0 + row) << 10) + hk + col);
      float4 f0 = gp[0], f1 = gp[1], f2 = gp[2], f3 = gp[3];
      uint4 a, b;
      a.x = (unsigned)f2bf(f0.x) | ((unsigned)f2bf(f0.y) << 16);
      a.y = (unsigned)f2bf(f0.z) | ((unsigned)f2bf(f0.w) << 16);
      a.z = (unsigned)f2bf(f1.x) | ((unsigned)f2bf(f1.y) << 16);
      a.w = (unsigned)f2bf(f1.z) | ((unsigned)f2bf(f1.w) << 16);
      b.x = (unsigned)f2bf(f2.x) | ((unsigned)f2bf(f2.y) << 16);
      b.y = (unsigned)f2bf(f2.z) | ((unsigned)f2bf(f2.w) << 16);
      b.z = (unsigned)f2bf(f3.x) | ((unsigned)f2bf(f3.y) << 16);
      b.w = (unsigned)f2bf(f3.z) | ((unsigned)f2bf(f3.w) << 16);
      unsigned short* dst = AH + row * APITCH + col;
      *(uint4*)dst = a;
      *(uint4*)(dst + 8) = b;
    }
  }
  __syncthreads();

  // B frag offsets within a tile: lane covers [nt*1KB, +1KB) contiguous
  int boffn[8];
#pragma unroll
  for (int nt = 0; nt < 8; ++nt)
    boffn[nt] = (((w << 7) + (nt << 4) + m) << 5) + (q << 3);
  const unsigned short* w1base = w1b + (blockIdx.y << 18);  // half*16 tiles

  f32x4 acc[4][8];
#pragma unroll
  for (int i = 0; i < 4; ++i)
#pragma unroll
    for (int j = 0; j < 8; ++j) acc[i][j] = (f32x4){0.f, 0.f, 0.f, 0.f};

#pragma unroll
  for (int it = 0; it < 16; ++it) {
    const unsigned short* bt = w1base + (it << 14);   // tile it
    bf16x8 bfr[8];
#pragma unroll
    for (int nt = 0; nt < 8; ++nt)
      bfr[nt] = *(const bf16x8*)(bt + boffn[nt]);
    bf16x8 af[4];
#pragma unroll
    for (int mt = 0; mt < 4; ++mt)
      af[mt] = *(const bf16x8*)(AH + ((mt << 4) + m) * APITCH + (it << 5) + (q << 3));
#pragma unroll
    for (int mt = 0; mt < 4; ++mt)
#pragma unroll
      for (int nt = 0; nt < 8; ++nt)
        acc[mt][nt] = __builtin_amdgcn_mfma_f32_16x16x32_bf16(af[mt], bfr[nt],
                                                              acc[mt][nt], 0, 0, 0);
  }
  __syncthreads();   // all waves done reading AH -> Eb may overlay it

  // ---- epilogue: 2 passes of 32 rows; wave-local repack + coalesced fp8
  // stores. C/D layout: col = lane&15, row = (lane>>4)*4 + reg.
#pragma unroll
  for (int pass = 0; pass < 2; ++pass) {
#pragma unroll
    for (int mh = 0; mh < 2; ++mh) {
      int mt = (pass << 1) + mh;
#pragma unroll
      for (int r = 0; r < 4; ++r) {
        int rr = (mh << 4) + ((lane >> 4) << 2) + r;   // 0..31
#pragma unroll
        for (int nt = 0; nt < 8; ++nt)
          Eb[((w << 5) + rr) * 136 + (nt << 4) + (lane & 15)] = f2bf(acc[mt][nt][r]);
      }
    }
    // 32 rows x 128 cols = 512 8-byte tasks = 8 iters x 64 lanes
#pragma unroll
    for (int i = 0; i < 8; ++i) {
      int task = (i << 6) + lane;
      int rr = task >> 4;
      int ck = task & 15;
      uint4 v = *(const uint4*)&Eb[((w << 5) + rr) * 136 + (ck << 3)];
      float f0 = bf2f(v.x & 0xffff), f1 = bf2f(v.x >> 16);
      float f2 = bf2f(v.y & 0xffff), f3 = bf2f(v.y >> 16);
      float f4 = bf2f(v.z & 0xffff), f5 = bf2f(v.z >> 16);
      float f6 = bf2f(v.w & 0xffff), f7 = bf2f(v.w >> 16);
      uint2 o;
      o.x = __builtin_amdgcn_cvt_pk_fp8_f32(f0, f1, 0, false);
      o.x = __builtin_amdgcn_cvt_pk_fp8_f32(f2, f3, o.x, true);
      o.y = __builtin_amdgcn_cvt_pk_fp8_f32(f4, f5, 0, false);
      o.y = __builtin_amdgcn_cvt_pk_fp8_f32(f6, f7, o.y, true);
      int grow = r0 + (pass << 5) + rr;
      int col = (w << 7) + (ck << 3);
      if (hk == 0) {
        *(uint2*)(Wq + (grow << 10) + col) = o;              // U[r]
      } else if (grow >= 32) {
        *(uint2*)(Wq + ((grow - 32) << 10) + 512 + col) = o; // V[r] -> row r-32
      }
    }
    // Eb[w] band is wave-local; no barrier between passes needed
  }
}

// ---------------- span_eval: 1 span per half-wave, LDS meta, depth-3 pipeline ----
#define SPB 64
__global__ __launch_bounds__(256) void span_eval(
    const unsigned char* __restrict__ Wq,
    const int* __restrict__ bids, const int* __restrict__ begins,
    const int* __restrict__ ends, const int* __restrict__ flags,
    const float* __restrict__ weights,
    const float* __restrict__ b1, const float* __restrict__ w2,
    const float* __restrict__ b2, float* __restrict__ partials) {
  __shared__ int oB[SPB], oE[SPB], sfl[SPB];
  __shared__ float swt[SPB];
  __shared__ float red[4][3];
  const int t = threadIdx.x;
  const int lane = t & 63;
  const int w = t >> 6;
  const int h = lane >> 5;          // half-wave
  const int hl = lane & 31;
  const int sbase = blockIdx.x * SPB;

  if (t < SPB) {
    int s = sbase + t;
    int b = bids[s], bg = begins[s], en = ends[s];
    oB[t] = (((bg - 1) << 5) + b) << 10;   // row b-1: [U[b-1] | V[b]]
    oE[t] = (((en - 1) << 5) + b) << 10;   // row e-1: [U[e-1] | V[e]]
    sfl[t] = flags[s];
    swt[t] = weights[s];
  }
  __syncthreads();

  const int sp0 = ((w << 1) + h) << 3;   // my half-wave's first span (block-local)
  const int c0 = hl << 4;                // 16 u-cols per lane
  float b1v[16], w2v[16];
#pragma unroll
  for (int q = 0; q < 4; ++q) {
    float4 bv = *(const float4*)(b1 + c0 + (q << 2));
    float4 wv = *(const float4*)(w2 + c0 + (q << 2));
    b1v[(q << 2) + 0] = bv.x; b1v[(q << 2) + 1] = bv.y;
    b1v[(q << 2) + 2] = bv.z; b1v[(q << 2) + 3] = bv.w;
    w2v[(q << 2) + 0] = wv.x; w2v[(q << 2) + 1] = wv.y;
    w2v[(q << 2) + 2] = wv.z; w2v[(q << 2) + 3] = wv.w;
  }

  auto dec = [](unsigned int v, float* f) {
    f32x2 a = __builtin_amdgcn_cvt_pk_f32_fp8(v, false);
    f32x2 b = __builtin_amdgcn_cvt_pk_f32_fp8(v, true);
    f[0] = a[0]; f[1] = a[1]; f[2] = b[0]; f[3] = b[1];
  };

  uint4 BU[3], BV[3], EU[3], EV[3];
  auto ld = [&](int slot, int j) {
    int ob = oB[sp0 + j], oe = oE[sp0 + j];
    BU[slot] = *(const uint4*)(Wq + ob + c0);        // U[b-1] chunk
    BV[slot] = *(const uint4*)(Wq + ob + 512 + c0);  // V[b]   chunk
    EU[slot] = *(const uint4*)(Wq + oe + c0);        // U[e-1] chunk
    EV[slot] = *(const uint4*)(Wq + oe + 512 + c0);  // V[e]   chunk
  };
  ld(0, 0); ld(1, 1); ld(2, 2);

  float mylogit = 0.f;
#pragma unroll
  for (int j = 0; j < 8; ++j) {
    const int slot = j % 3;
    float buf[16], bvf[16], euf[16], evf[16];
    dec(BU[slot].x, buf); dec(BU[slot].y, buf + 4);
    dec(BU[slot].z, buf + 8); dec(BU[slot].w, buf + 12);
    dec(BV[slot].x, bvf); dec(BV[slot].y, bvf + 4);
    dec(BV[slot].z, bvf + 8); dec(BV[slot].w, bvf + 12);
    dec(EU[slot].x, euf); dec(EU[slot].y, euf + 4);
    dec(EU[slot].z, euf + 8); dec(EU[slot].w, euf + 12);
    dec(EV[slot].x, evf); dec(EV[slot].y, evf + 4);
    dec(EV[slot].z, evf + 8); dec(EV[slot].w, evf + 12);
    if (j + 3 < 8) ld(slot, j + 3);
    float sv = 0.f;
#pragma unroll
    for (int k = 0; k < 16; ++k) {
      float zp = euf[k] - buf[k] + bvf[k] - evf[k] + b1v[k];
      sv += fmaxf(zp, 0.f) * w2v[k];
    }
    sv += __shfl_xor(sv, 1);
    sv += __shfl_xor(sv, 2);
    sv += __shfl_xor(sv, 4);
    sv += __shfl_xor(sv, 8);
    sv += __shfl_xor(sv, 16);       // reduce within half-wave
    if (hl == j) mylogit = sv;      // lane h*32+j parks span sp0+j
  }

  // span w*16+l (l<16) parked at lane ((l&8)<<2)+(l&7)
  mylogit = __shfl(mylogit, ((lane & 8) << 2) + (lane & 7));

  float pos_t = 0.f, neg_t = 0.f, cnt_t = 0.f;
  if (lane < 16) {
    int sl = (w << 4) + lane;       // block-local span id
    float logit = mylogit + b2[0];
    float p = 1.f / (1.f + expf(-logit));
    p = fminf(fmaxf(p, 1e-7f), 1.f - 1e-7f);
    int fl = sfl[sl];
    float bce = (fl == 1) ? -logf(p) : -logf(1.f - p);
    float term = swt[sl] * bce;
    pos_t = (fl == 1) ? term : 0.f;
    neg_t = (fl == 1) ? 0.f : term;
    cnt_t = (fl == 1) ? 1.f : 0.f;
  }
#pragma unroll
  for (int off = 1; off < 64; off <<= 1) {
    pos_t += __shfl_xor(pos_t, off);
    neg_t += __shfl_xor(neg_t, off);
    cnt_t += __shfl_xor(cnt_t, off);
  }
  if (lane == 0) { red[w][0] = pos_t; red[w][1] = neg_t; red[w][2] = cnt_t; }
  __syncthreads();
  if (t == 0) {
    partials[(blockIdx.x << 2) + 0] = red[0][0] + red[1][0] + red[2][0] + red[3][0];
    partials[(blockIdx.x << 2) + 1] = red[0][1] + red[1][1] + red[2][1] + red[3][1];
    partials[(blockIdx.x << 2) + 2] = red[0][2] + red[1][2] + red[2][2] + red[3][2];
  }
}

// ---------------- finalize ----------------
__global__ void finalize(const float* __restrict__ parts, int nblk,
                         float* __restrict__ out, int nspans) {
  __shared__ float sp[4], sn[4], sc[4];
  float P = 0.f, Ng = 0.f, C = 0.f;
  for (int i = threadIdx.x; i < nblk; i += 256) {
    P += parts[(i << 2) + 0];
    Ng += parts[(i << 2) + 1];
    C += parts[(i << 2) + 2];
  }
#pragma unroll
  for (int off = 1; off < 64; off <<= 1) {
    P += __shfl_xor(P, off);
    Ng += __shfl_xor(Ng, off);
    C += __shfl_xor(C, off);
  }
  int w = threadIdx.x >> 6;
  if ((threadIdx.x & 63) == 0) { sp[w] = P; sn[w] = Ng; sc[w] = C; }
  __syncthreads();
  if (threadIdx.x == 0) {
    P = sp[0] + sp[1] + sp[2] + sp[3];
    Ng = sn[0] + sn[1] + sn[2] + sn[3];
    C = sc[0] + sc[1] + sc[2] + sc[3];
    float scale = 2.f * C / (float)nspans;
    out[0] = (P + scale * Ng) / (float)nspans;
  }
}

extern "C" void kernel_launch(void* const* d_in, const int* in_sizes, int n_in,
                              void* d_out, int out_size, void* d_ws, size_t ws_size,
                              hipStream_t stream) {
  const float* hidden = (const float*)d_in[0];
  const int* bids     = (const int*)d_in[1];
  const int* begins   = (const int*)d_in[2];
  const int* ends     = (const int*)d_in[3];
  const int* flags    = (const int*)d_in[4];
  const float* weights = (const float*)d_in[5];
  const float* W1 = (const float*)d_in[6];
  const float* b1 = (const float*)d_in[7];
  const float* W2 = (const float*)d_in[8];
  const float* b2 = (const float*)d_in[9];
  float* out = (float*)d_out;
  const int nspans = in_sizes[1];       // 131072
  const int nblk = nspans / SPB;        // 2048

  float* partials = (float*)d_ws;                                    // 32 KiB
  unsigned short* W1b = (unsigned short*)((char*)d_ws + (1 << 18));  // 1 MiB blocked
  unsigned char* Wq = (unsigned char*)((char*)d_ws + (2 << 20));     // 16.8 MiB

  w1_blocked<<<256, 256, 0, stream>>>(W1, W1b);
  proj_gemm<<<dim3(256, 2), 256, 0, stream>>>(hidden, W1b, Wq);
  span_eval<<<nblk, 256, 0, stream>>>(Wq, bids, begins, ends, flags, weights,
                                      b1, W2, b2, partials);
  finalize<<<1, 256, 0, stream>>>(partials, nblk, out, nspans);
}